// Round 2
// baseline (967.694 us; speedup 1.0000x reference)
//
#include <hip/hip_runtime.h>
#include <hip/hip_bf16.h>

#define VOCAB  50257
#define KCTX   8
#define EMBED  64
#define HIDDEN 1024
#define BATCH  256

typedef __attribute__((ext_vector_type(8))) short bf16x8;
typedef __attribute__((ext_vector_type(4))) float f32x4;

__device__ __forceinline__ unsigned short f2bf(float f) {
  union { float f; unsigned u; } un; un.f = f;
  unsigned r = un.u + 0x7FFFu + ((un.u >> 16) & 1u);   // round-to-nearest-even
  return (unsigned short)(r >> 16);
}

__device__ __forceinline__ float silu_f(float x) { return x / (1.f + __expf(-x)); }

// ---------------------------------------------------------------------------
// Kernel 1: scan the dense one-hot context to recover (index, value) per (b,k).
// 412 MB read, pure HBM-bound grid-stride float4 scan.
// ---------------------------------------------------------------------------
__global__ __launch_bounds__(256) void k_scan(const float* __restrict__ ctx,
                                              int* __restrict__ idx,
                                              float* __restrict__ val,
                                              long n4) {
  long i = (long)blockIdx.x * blockDim.x + threadIdx.x;
  long stride = (long)gridDim.x * blockDim.x;
  const float4* c4 = (const float4*)ctx;
  for (; i < n4; i += stride) {
    float4 v = c4[i];
    if (v.x != 0.f || v.y != 0.f || v.z != 0.f || v.w != 0.f) {
      float vals[4] = {v.x, v.y, v.z, v.w};
      long base = i * 4;
      #pragma unroll
      for (int j = 0; j < 4; ++j) {
        if (vals[j] != 0.f) {
          long g = base + j;                 // g = b*K*V + k*V + v
          int bk = (int)(g / VOCAB);
          int vv = (int)(g - (long)bk * VOCAB);
          idx[bk] = vv;
          val[bk] = vals[j];
        }
      }
    }
  }
}

// ---------------------------------------------------------------------------
// Kernel 2: gather embeddings + layer 1 (K=512) + SiLU.  2 rows per block.
// ---------------------------------------------------------------------------
__global__ __launch_bounds__(256) void k_gather_l1(const int* __restrict__ idx,
                                                   const float* __restrict__ val,
                                                   const float* __restrict__ embed_w,
                                                   const float* __restrict__ W1,
                                                   const float* __restrict__ b1,
                                                   float* __restrict__ x1) {
  __shared__ float x0[2][512];
  int r0 = blockIdx.x * 2;
  int tid = threadIdx.x;
  for (int e = tid; e < 2 * 512; e += 256) {
    int rr = e >> 9, j = e & 511;
    int ks = j >> 6, em = j & 63;
    int bk = (r0 + rr) * KCTX + ks;
    x0[rr][j] = embed_w[idx[bk] * EMBED + em] * val[bk];
  }
  __syncthreads();

  float acc[2][4];
  #pragma unroll
  for (int c = 0; c < 4; ++c) {
    float bb = b1[tid + c * 256];
    acc[0][c] = bb; acc[1][c] = bb;
  }
  for (int j = 0; j < 512; ++j) {
    float xa = x0[0][j], xb = x0[1][j];
    const float* wr = W1 + j * HIDDEN + tid;
    #pragma unroll
    for (int c = 0; c < 4; ++c) {
      float w = wr[c * 256];
      acc[0][c] = fmaf(xa, w, acc[0][c]);
      acc[1][c] = fmaf(xb, w, acc[1][c]);
    }
  }
  #pragma unroll
  for (int c = 0; c < 4; ++c) {
    x1[(r0 + 0) * HIDDEN + tid + c * 256] = silu_f(acc[0][c]);
    x1[(r0 + 1) * HIDDEN + tid + c * 256] = silu_f(acc[1][c]);
  }
}

// ---------------------------------------------------------------------------
// Kernel 3: layer 2 (K=1024) + SiLU, output cast to bf16 for the MFMA layer.
// ---------------------------------------------------------------------------
__global__ __launch_bounds__(256) void k_l2(const float* __restrict__ x1,
                                            const float* __restrict__ W2,
                                            const float* __restrict__ b2,
                                            short* __restrict__ x2) {
  __shared__ float xs[2][1024];
  int r0 = blockIdx.x * 2;
  int tid = threadIdx.x;
  for (int e = tid; e < 2 * 1024; e += 256) {
    int rr = e >> 10, j = e & 1023;
    xs[rr][j] = x1[(r0 + rr) * HIDDEN + j];
  }
  __syncthreads();

  float acc[2][4];
  #pragma unroll
  for (int c = 0; c < 4; ++c) {
    float bb = b2[tid + c * 256];
    acc[0][c] = bb; acc[1][c] = bb;
  }
  for (int j = 0; j < 1024; ++j) {
    float xa = xs[0][j], xb = xs[1][j];
    const float* wr = W2 + j * HIDDEN + tid;
    #pragma unroll
    for (int c = 0; c < 4; ++c) {
      float w = wr[c * 256];
      acc[0][c] = fmaf(xa, w, acc[0][c]);
      acc[1][c] = fmaf(xb, w, acc[1][c]);
    }
  }
  #pragma unroll
  for (int c = 0; c < 4; ++c) {
    x2[(r0 + 0) * HIDDEN + tid + c * 256] = (short)f2bf(silu_f(acc[0][c]));
    x2[(r0 + 1) * HIDDEN + tid + c * 256] = (short)f2bf(silu_f(acc[1][c]));
  }
}

// ---------------------------------------------------------------------------
// Kernel 4: layer 3 via bf16 MFMA.  Block = 256 thr = 4 waves; tile = 256 rows
// (full batch -> W3 read exactly once) x 64 cols.  W3 converted fp32->bf16 on
// the fly.  C/D layout: col = lane&15, row = (lane>>4)*4 + reg  [guide §3].
// ---------------------------------------------------------------------------
__global__ __launch_bounds__(256) void k_l3(const short* __restrict__ x2,
                                            const float* __restrict__ W3,
                                            const float* __restrict__ b3,
                                            float* __restrict__ out) {
  int tid = threadIdx.x;
  int wave = tid >> 6, lane = tid & 63;
  int l15 = lane & 15, l4 = lane >> 4;
  int col0 = blockIdx.x * 64;
  int wrow = wave * 64;

  f32x4 acc[4][4];
  #pragma unroll
  for (int mi = 0; mi < 4; ++mi)
    #pragma unroll
    for (int ni = 0; ni < 4; ++ni)
      acc[mi][ni] = (f32x4){0.f, 0.f, 0.f, 0.f};

  for (int k0 = 0; k0 < HIDDEN; k0 += 32) {
    int ka = k0 + l4 * 8;                    // this lane's k-base (8 contiguous)
    bf16x8 a[4];
    #pragma unroll
    for (int mi = 0; mi < 4; ++mi) {
      int row = wrow + mi * 16 + l15;
      a[mi] = *reinterpret_cast<const bf16x8*>(x2 + row * HIDDEN + ka);
    }
    const float* pBk = W3 + (long)ka * VOCAB;
    #pragma unroll
    for (int ni = 0; ni < 4; ++ni) {
      int col = col0 + ni * 16 + l15;
      bool ok = col < VOCAB;
      const float* pB = pBk + (ok ? col : 0);
      float bv[8];
      #pragma unroll
      for (int j = 0; j < 8; ++j) bv[j] = ok ? pB[j * VOCAB] : 0.f;
      bf16x8 b;
      #pragma unroll
      for (int j = 0; j < 8; ++j) b[j] = (short)f2bf(bv[j]);
      #pragma unroll
      for (int mi = 0; mi < 4; ++mi)
        acc[mi][ni] = __builtin_amdgcn_mfma_f32_16x16x32_bf16(a[mi], b, acc[mi][ni], 0, 0, 0);
    }
  }

  #pragma unroll
  for (int ni = 0; ni < 4; ++ni) {
    int col = col0 + ni * 16 + l15;
    if (col < VOCAB) {
      float bb = b3[col];
      #pragma unroll
      for (int mi = 0; mi < 4; ++mi) {
        #pragma unroll
        for (int r = 0; r < 4; ++r) {
          int row = wrow + mi * 16 + l4 * 4 + r;
          out[(long)row * VOCAB + col] = acc[mi][ni][r] + bb;
        }
      }
    }
  }
}

// ---------------------------------------------------------------------------
extern "C" void kernel_launch(void* const* d_in, const int* in_sizes, int n_in,
                              void* d_out, int out_size, void* d_ws, size_t ws_size,
                              hipStream_t stream) {
  const float* ctx     = (const float*)d_in[0];
  const float* embed_w = (const float*)d_in[1];
  const float* W1      = (const float*)d_in[2];
  const float* b1      = (const float*)d_in[3];
  const float* W2      = (const float*)d_in[4];
  const float* b2      = (const float*)d_in[5];
  const float* W3      = (const float*)d_in[6];
  const float* b3      = (const float*)d_in[7];
  float* out = (float*)d_out;

  char* w = (char*)d_ws;
  int*   idx = (int*)w;                                   // 8 KB
  float* val = (float*)(w + 8192);                        // 8 KB
  float* x1  = (float*)(w + 16384);                       // 1 MB
  short* x2  = (short*)(w + 16384 + 1048576);             // 512 KB

  long n4 = (long)BATCH * KCTX * VOCAB / 4;
  k_scan<<<2048, 256, 0, stream>>>(ctx, idx, val, n4);
  k_gather_l1<<<BATCH / 2, 256, 0, stream>>>(idx, val, embed_w, W1, b1, x1);
  k_l2<<<BATCH / 2, 256, 0, stream>>>(x1, W2, b2, x2);
  k_l3<<<(VOCAB + 63) / 64, 256, 0, stream>>>(x2, W3, b3, out);
}